// Round 21
// baseline (117.818 us; speedup 1.0000x reference)
//
#include <hip/hip_runtime.h>
#include <hip/hip_cooperative_groups.h>

namespace cg = cooperative_groups;

#define N_NODES 100000
#define N_EDGES 6400000
#define RANGES 4
#define RANGE_S 25000   // nodes per range
#define NB 64           // chunks; CHUNK = 100000 edges
#define CHUNK (N_EDGES / NB)
#define FIX_SCALE 1048576.0f        // 2^20
#define FIX_INV   (1.0f / 1048576.0f)

#define TBLOCKS 256
#define TTHREADS 1024
#define EPB 25000                   // edges per block, phase 1 (quarter chunk)
#define GPB (EPB / 8)               // 3125 groups of 8
#define LDSN 80000                  // nodes resident in LDS (bf16, 160000 B)

// ============ fallback path: direct device atomics ============
__global__ void zero_out_kernel(float* __restrict__ out, int n) {
    int i = blockIdx.x * blockDim.x + threadIdx.x;
    if (i < n) out[i] = 0.0f;
}

__global__ void __launch_bounds__(256) scatter_direct_kernel(
        const float* __restrict__ x, const int* __restrict__ ei,
        const float* __restrict__ w, float* __restrict__ out) {
    int t = blockIdx.x * blockDim.x + threadIdx.x;
    int e0 = t * 4;
    if (e0 >= N_EDGES) return;
    int4   s4 = *reinterpret_cast<const int4*>(ei + e0);
    int4   d4 = *reinterpret_cast<const int4*>(ei + N_EDGES + e0);
    float4 w4 = *reinterpret_cast<const float4*>(w + e0);
    atomicAdd(&out[s4.x], w4.x * x[d4.x]);
    atomicAdd(&out[s4.y], w4.y * x[d4.y]);
    atomicAdd(&out[s4.z], w4.z * x[d4.z]);
    atomicAdd(&out[s4.w], w4.w * x[d4.w]);
}

// ============ main path: fused cooperative kernel ============
__device__ __forceinline__ unsigned bf16_rne(float f) {
    unsigned b = __float_as_uint(f);
    b += 0x7FFFu + ((b >> 16) & 1u);
    return b >> 16;
}
__device__ __forceinline__ float bf16_to_f(unsigned h) {
    return __uint_as_float(h << 16);
}

// One block per CU (160KB LDS). Phase 1: transform quarter (slot&3) of chunk
// c=(slot>>2)*8+xcd (msg stays XCD-local). Phase 2: bin range (slot&3) of the
// SAME chunk c from the same XCD's L2. Phase 3: reduce. Two grid syncs.
__global__ void __launch_bounds__(TTHREADS, 4) fused_kernel(
        const float* __restrict__ x, const int* __restrict__ ei,
        const float* __restrict__ w, unsigned short* __restrict__ msg,
        unsigned short* __restrict__ partial, float* __restrict__ out) {
    __shared__ __align__(16) unsigned char smem[160000];
    unsigned short* xh  = reinterpret_cast<unsigned short*>(smem);  // phase 1
    int*            bins = reinterpret_cast<int*>(smem);            // phase 2

    const int tid  = threadIdx.x;
    const int b    = blockIdx.x;       // 0..255
    const int xcd  = b & 7;
    const int slot = b >> 3;           // 0..31
    const int rq   = slot & 3;         // quarter (ph1) / range (ph2)
    const int c    = (slot >> 2) * 8 + xcd;   // chunk 0..63, XCD-stable
    const int* dstp = ei + N_EDGES;

    // ---------------- phase 1: transform ----------------
    {
        // stage nodes [0, LDSN) as bf16, coalesced
        const float4* xs = reinterpret_cast<const float4*>(x);
        for (int j = tid; j < LDSN / 8; j += TTHREADS) {
            float4 f0 = xs[j * 2], f1 = xs[j * 2 + 1];
            uint4 pk;
            pk.x = bf16_rne(f0.x) | (bf16_rne(f0.y) << 16);
            pk.y = bf16_rne(f0.z) | (bf16_rne(f0.w) << 16);
            pk.z = bf16_rne(f1.x) | (bf16_rne(f1.y) << 16);
            pk.w = bf16_rne(f1.z) | (bf16_rne(f1.w) << 16);
            *reinterpret_cast<uint4*>(&xh[j * 8]) = pk;
        }
        __syncthreads();

        const int base = c * CHUNK + rq * EPB;
        #pragma unroll
        for (int k = 0; k < 4; ++k) {
            const int idx = k * TTHREADS + tid;
            if (idx < GPB) {
                const int e0 = base + idx * 8;
                int4   da = *reinterpret_cast<const int4*>(dstp + e0);
                int4   db = *reinterpret_cast<const int4*>(dstp + e0 + 4);
                float4 wa = *reinterpret_cast<const float4*>(w + e0);
                float4 wb = *reinterpret_cast<const float4*>(w + e0 + 4);

                unsigned a0 = (unsigned)da.x, a1 = (unsigned)da.y,
                         a2 = (unsigned)da.z, a3 = (unsigned)da.w,
                         a4 = (unsigned)db.x, a5 = (unsigned)db.y,
                         a6 = (unsigned)db.z, a7 = (unsigned)db.w;
                float v0 = bf16_to_f(xh[a0 < LDSN ? a0 : 0u]);
                float v1 = bf16_to_f(xh[a1 < LDSN ? a1 : 0u]);
                float v2 = bf16_to_f(xh[a2 < LDSN ? a2 : 0u]);
                float v3 = bf16_to_f(xh[a3 < LDSN ? a3 : 0u]);
                float v4 = bf16_to_f(xh[a4 < LDSN ? a4 : 0u]);
                float v5 = bf16_to_f(xh[a5 < LDSN ? a5 : 0u]);
                float v6 = bf16_to_f(xh[a6 < LDSN ? a6 : 0u]);
                float v7 = bf16_to_f(xh[a7 < LDSN ? a7 : 0u]);
                if (a0 >= LDSN) v0 = x[a0];
                if (a1 >= LDSN) v1 = x[a1];
                if (a2 >= LDSN) v2 = x[a2];
                if (a3 >= LDSN) v3 = x[a3];
                if (a4 >= LDSN) v4 = x[a4];
                if (a5 >= LDSN) v5 = x[a5];
                if (a6 >= LDSN) v6 = x[a6];
                if (a7 >= LDSN) v7 = x[a7];

                uint4 o;
                o.x = bf16_rne(wa.x * v0) | (bf16_rne(wa.y * v1) << 16);
                o.y = bf16_rne(wa.z * v2) | (bf16_rne(wa.w * v3) << 16);
                o.z = bf16_rne(wb.x * v4) | (bf16_rne(wb.y * v5) << 16);
                o.w = bf16_rne(wb.z * v6) | (bf16_rne(wb.w * v7) << 16);
                *reinterpret_cast<uint4*>(msg + e0) = o;
            }
        }
    }

    cg::this_grid().sync();

    // ---------------- phase 2: bin range rq of chunk c ----------------
    {
        for (int i = tid; i < RANGE_S; i += TTHREADS) bins[i] = 0;
        __syncthreads();

        const int base = c * CHUNK;
        const int end  = base + CHUNK;
        const int lo   = rq * RANGE_S;

        for (int e = base + tid * 8; e < end; e += TTHREADS * 8) {
            int4 sa = *reinterpret_cast<const int4*>(ei + e);
            int4 sb = *reinterpret_cast<const int4*>(ei + e + 4);
            uint4 mm = *reinterpret_cast<const uint4*>(msg + e);

            unsigned a[8] = {(unsigned)(sa.x-lo),(unsigned)(sa.y-lo),(unsigned)(sa.z-lo),(unsigned)(sa.w-lo),
                             (unsigned)(sb.x-lo),(unsigned)(sb.y-lo),(unsigned)(sb.z-lo),(unsigned)(sb.w-lo)};
            float f[8] = {
                __uint_as_float((mm.x & 0xFFFFu) << 16), __uint_as_float(mm.x & 0xFFFF0000u),
                __uint_as_float((mm.y & 0xFFFFu) << 16), __uint_as_float(mm.y & 0xFFFF0000u),
                __uint_as_float((mm.z & 0xFFFFu) << 16), __uint_as_float(mm.z & 0xFFFF0000u),
                __uint_as_float((mm.w & 0xFFFFu) << 16), __uint_as_float(mm.w & 0xFFFF0000u)
            };
            int mi[8];
            #pragma unroll
            for (int k = 0; k < 8; ++k) mi[k] = (int)__builtin_rintf(f[k] * FIX_SCALE);
            #pragma unroll
            for (int k = 0; k < 8; ++k) {
                if (a[k] < RANGE_S) atomicAdd(&bins[a[k]], mi[k]);
            }
        }
        __syncthreads();

        unsigned short* outp = partial + (size_t)(rq * NB + c) * RANGE_S;
        for (int i = tid; i < RANGE_S / 4; i += TTHREADS) {
            int4 v = *reinterpret_cast<const int4*>(&bins[i * 4]);
            uint2 pk;
            pk.x = bf16_rne((float)v.x * FIX_INV) | (bf16_rne((float)v.y * FIX_INV) << 16);
            pk.y = bf16_rne((float)v.z * FIX_INV) | (bf16_rne((float)v.w * FIX_INV) << 16);
            *reinterpret_cast<uint2*>(outp + i * 4) = pk;
        }
    }

    cg::this_grid().sync();

    // ---------------- phase 3: reduce ----------------
    {
        int t = b * TTHREADS + tid;
        int n0 = t * 4;
        if (n0 < N_NODES) {
            int r = n0 / RANGE_S;
            int s = n0 - r * RANGE_S;
            const unsigned short* bp = partial + (size_t)(r * NB) * RANGE_S + s;
            float4 acc = make_float4(0.f, 0.f, 0.f, 0.f);
            for (int j = 0; j < NB; ++j) {
                uint2 v = *reinterpret_cast<const uint2*>(bp + (size_t)j * RANGE_S);
                acc.x += bf16_to_f(v.x & 0xFFFFu);
                acc.y += bf16_to_f(v.x >> 16);
                acc.z += bf16_to_f(v.y & 0xFFFFu);
                acc.w += bf16_to_f(v.y >> 16);
            }
            *reinterpret_cast<float4*>(out + n0) = acc;
        }
    }
}

extern "C" void kernel_launch(void* const* d_in, const int* in_sizes, int n_in,
                              void* d_out, int out_size, void* d_ws, size_t ws_size,
                              hipStream_t stream) {
    const float* x   = (const float*)d_in[0];
    const int*   ei  = (const int*)d_in[1];
    const float* w   = (const float*)d_in[2];
    float*       out = (float*)d_out;

    const size_t msg_bytes     = (size_t)N_EDGES * 2;                 // 12.8 MB
    const size_t partial_bytes = (size_t)RANGES * NB * RANGE_S * 2;   // 12.8 MB

    if (ws_size >= msg_bytes + partial_bytes) {
        unsigned short* msg     = (unsigned short*)d_ws;
        unsigned short* partial = (unsigned short*)((char*)d_ws + msg_bytes);
        void* args[] = { (void*)&x, (void*)&ei, (void*)&w,
                         (void*)&msg, (void*)&partial, (void*)&out };
        hipLaunchCooperativeKernel((const void*)fused_kernel,
                                   dim3(TBLOCKS), dim3(TTHREADS),
                                   args, 0, stream);
    } else {
        zero_out_kernel<<<(N_NODES + 255) / 256, 256, 0, stream>>>(out, N_NODES);
        scatter_direct_kernel<<<(N_EDGES / 4 + 255) / 256, 256, 0, stream>>>(x, ei, w, out);
    }
}

// Round 22
// 40.145 us; speedup vs baseline: 2.9348x; 2.9348x over previous
//
#include <hip/hip_runtime.h>

#define N_NODES 100000
#define N_EDGES 6400000
#define RANGES 4
#define RANGE_S 25000   // nodes per range; RANGES * RANGE_S == N_NODES
#define NB 64           // chunks; chunk = 100000 edges
#define BLK 1024
#define FIX_SCALE 1048576.0f        // 2^20
#define FIX_INV   (1.0f / 1048576.0f)

// transform v6 geometry (R19-proven best): SINGLE pass, 80K nodes in 160KB LDS
#define TBLOCKS 256
#define TTHREADS 1024
#define EPB (N_EDGES / TBLOCKS)     // 25000 edges per block
#define GPB (EPB / 8)               // 3125 groups of 8
#define LDSN 80000                  // nodes resident in LDS (bf16, 160000 B)

// ============ fallback path A: direct device atomics ============
__global__ void zero_out_kernel(float* __restrict__ out, int n) {
    int i = blockIdx.x * blockDim.x + threadIdx.x;
    if (i < n) out[i] = 0.0f;
}

__global__ void __launch_bounds__(256) scatter_direct_kernel(
        const float* __restrict__ x, const int* __restrict__ ei,
        const float* __restrict__ w, float* __restrict__ out) {
    int t = blockIdx.x * blockDim.x + threadIdx.x;
    int e0 = t * 4;
    if (e0 >= N_EDGES) return;
    int4   s4 = *reinterpret_cast<const int4*>(ei + e0);
    int4   d4 = *reinterpret_cast<const int4*>(ei + N_EDGES + e0);
    float4 w4 = *reinterpret_cast<const float4*>(w + e0);
    atomicAdd(&out[s4.x], w4.x * x[d4.x]);
    atomicAdd(&out[s4.y], w4.y * x[d4.y]);
    atomicAdd(&out[s4.z], w4.z * x[d4.z]);
    atomicAdd(&out[s4.w], w4.w * x[d4.w]);
}

// ============ main path ============
__device__ __forceinline__ unsigned bf16_rne(float f) {
    unsigned b = __float_as_uint(f);
    b += 0x7FFFu + ((b >> 16) & 1u);
    return b >> 16;
}
__device__ __forceinline__ float bf16_to_f(unsigned h) {
    return __uint_as_float(h << 16);
}

// Phase 1 v6 (R19): single-pass LDS gather. Nodes [0,80K) staged as bf16 in
// 160KB LDS; edges whose dst >= 80K take a predicated L2 load of f32 x.
__global__ void __launch_bounds__(TTHREADS, 4) transform_kernel(
        const float* __restrict__ x, const int* __restrict__ ei,
        const float* __restrict__ w, unsigned short* __restrict__ msg) {
    __shared__ unsigned short xh[LDSN];   // 160000 B
    const int tid  = threadIdx.x;
    const int base = blockIdx.x * EPB;
    const int* dstp = ei + N_EDGES;

    // stage nodes [0, LDSN) as bf16, coalesced
    const float4* xs = reinterpret_cast<const float4*>(x);
    for (int j = tid; j < LDSN / 8; j += TTHREADS) {
        float4 f0 = xs[j * 2], f1 = xs[j * 2 + 1];
        uint4 pk;
        pk.x = bf16_rne(f0.x) | (bf16_rne(f0.y) << 16);
        pk.y = bf16_rne(f0.z) | (bf16_rne(f0.w) << 16);
        pk.z = bf16_rne(f1.x) | (bf16_rne(f1.y) << 16);
        pk.w = bf16_rne(f1.z) | (bf16_rne(f1.w) << 16);
        *reinterpret_cast<uint4*>(&xh[j * 8]) = pk;
    }
    __syncthreads();

    #pragma unroll
    for (int k = 0; k < 4; ++k) {
        int idx = k * TTHREADS + tid;
        if (idx < GPB) {
            int e0 = base + idx * 8;
            int4   da = *reinterpret_cast<const int4*>(dstp + e0);
            int4   db = *reinterpret_cast<const int4*>(dstp + e0 + 4);
            float4 wa = *reinterpret_cast<const float4*>(w + e0);
            float4 wb = *reinterpret_cast<const float4*>(w + e0 + 4);

            unsigned a0 = (unsigned)da.x, a1 = (unsigned)da.y,
                     a2 = (unsigned)da.z, a3 = (unsigned)da.w,
                     a4 = (unsigned)db.x, a5 = (unsigned)db.y,
                     a6 = (unsigned)db.z, a7 = (unsigned)db.w;
            float v0 = bf16_to_f(xh[a0 < LDSN ? a0 : 0u]);
            float v1 = bf16_to_f(xh[a1 < LDSN ? a1 : 0u]);
            float v2 = bf16_to_f(xh[a2 < LDSN ? a2 : 0u]);
            float v3 = bf16_to_f(xh[a3 < LDSN ? a3 : 0u]);
            float v4 = bf16_to_f(xh[a4 < LDSN ? a4 : 0u]);
            float v5 = bf16_to_f(xh[a5 < LDSN ? a5 : 0u]);
            float v6 = bf16_to_f(xh[a6 < LDSN ? a6 : 0u]);
            float v7 = bf16_to_f(xh[a7 < LDSN ? a7 : 0u]);
            if (a0 >= LDSN) v0 = x[a0];
            if (a1 >= LDSN) v1 = x[a1];
            if (a2 >= LDSN) v2 = x[a2];
            if (a3 >= LDSN) v3 = x[a3];
            if (a4 >= LDSN) v4 = x[a4];
            if (a5 >= LDSN) v5 = x[a5];
            if (a6 >= LDSN) v6 = x[a6];
            if (a7 >= LDSN) v7 = x[a7];

            uint4 o;
            o.x = bf16_rne(wa.x * v0) | (bf16_rne(wa.y * v1) << 16);
            o.y = bf16_rne(wa.z * v2) | (bf16_rne(wa.w * v3) << 16);
            o.z = bf16_rne(wb.x * v4) | (bf16_rne(wb.y * v5) << 16);
            o.w = bf16_rne(wb.z * v6) | (bf16_rne(wb.w * v7) << 16);
            *reinterpret_cast<uint4*>(msg + e0) = o;
        }
    }
}

// Phase 2: 4 ranges x 100 KB int bins, XCD-sibling swizzle (R16-proven).
__global__ void __launch_bounds__(BLK) bin_kernel(
        const int* __restrict__ ei, const unsigned short* __restrict__ msg,
        unsigned short* __restrict__ partial) {
    __shared__ int bins[RANGE_S];   // 100 KB
    const int b    = blockIdx.x;    // 0..255
    const int xcd  = b & 7;
    const int slot = b >> 3;        // 0..31
    const int r    = slot & 3;      // range 0..3
    const int c    = (slot >> 2) * 8 + xcd;  // chunk 0..63 (siblings share XCD)

    for (int i = threadIdx.x; i < RANGE_S; i += BLK) bins[i] = 0;
    __syncthreads();

    const int chunk = N_EDGES / NB;   // 100000, % 8 == 0
    const int base  = c * chunk;
    const int end   = base + chunk;
    const int lo    = r * RANGE_S;

    for (int e = base + (int)threadIdx.x * 8; e < end; e += BLK * 8) {
        int4 sa = *reinterpret_cast<const int4*>(ei + e);
        int4 sb = *reinterpret_cast<const int4*>(ei + e + 4);
        uint4 mm = *reinterpret_cast<const uint4*>(msg + e);

        unsigned a[8] = {(unsigned)(sa.x-lo),(unsigned)(sa.y-lo),(unsigned)(sa.z-lo),(unsigned)(sa.w-lo),
                         (unsigned)(sb.x-lo),(unsigned)(sb.y-lo),(unsigned)(sb.z-lo),(unsigned)(sb.w-lo)};
        float f[8] = {
            __uint_as_float((mm.x & 0xFFFFu) << 16), __uint_as_float(mm.x & 0xFFFF0000u),
            __uint_as_float((mm.y & 0xFFFFu) << 16), __uint_as_float(mm.y & 0xFFFF0000u),
            __uint_as_float((mm.z & 0xFFFFu) << 16), __uint_as_float(mm.z & 0xFFFF0000u),
            __uint_as_float((mm.w & 0xFFFFu) << 16), __uint_as_float(mm.w & 0xFFFF0000u)
        };
        int mi[8];
        #pragma unroll
        for (int k = 0; k < 8; ++k) mi[k] = (int)__builtin_rintf(f[k] * FIX_SCALE);
        #pragma unroll
        for (int k = 0; k < 8; ++k) {
            if (a[k] < RANGE_S) atomicAdd(&bins[a[k]], mi[k]);   // integer LDS atomic
        }
    }
    __syncthreads();

    // bf16 writeout: 4 nodes per uint2
    unsigned short* outp = partial + (size_t)(r * NB + c) * RANGE_S;
    for (int i = threadIdx.x; i < RANGE_S / 4; i += BLK) {
        int4 v = *reinterpret_cast<const int4*>(&bins[i * 4]);
        uint2 pk;
        pk.x = bf16_rne((float)v.x * FIX_INV) | (bf16_rne((float)v.y * FIX_INV) << 16);
        pk.y = bf16_rne((float)v.z * FIX_INV) | (bf16_rne((float)v.w * FIX_INV) << 16);
        *reinterpret_cast<uint2*>(outp + i * 4) = pk;
    }
}

// Reduce: sum 64 bf16 chunk-partials per node in f32.
__global__ void reduce_range_kernel(const unsigned short* __restrict__ partial,
                                    float* __restrict__ out) {
    int i = blockIdx.x * blockDim.x + threadIdx.x;
    int n0 = i * 4;
    if (n0 >= N_NODES) return;
    int r = n0 / RANGE_S;
    int s = n0 - r * RANGE_S;          // RANGE_S % 4 == 0 -> no straddle
    const unsigned short* bp = partial + (size_t)(r * NB) * RANGE_S + s;
    float4 acc = make_float4(0.f, 0.f, 0.f, 0.f);
    for (int j = 0; j < NB; ++j) {
        uint2 v = *reinterpret_cast<const uint2*>(bp + (size_t)j * RANGE_S);
        acc.x += bf16_to_f(v.x & 0xFFFFu);
        acc.y += bf16_to_f(v.x >> 16);
        acc.z += bf16_to_f(v.y & 0xFFFFu);
        acc.w += bf16_to_f(v.y >> 16);
    }
    *reinterpret_cast<float4*>(out + n0) = acc;
}

extern "C" void kernel_launch(void* const* d_in, const int* in_sizes, int n_in,
                              void* d_out, int out_size, void* d_ws, size_t ws_size,
                              hipStream_t stream) {
    const float* x   = (const float*)d_in[0];
    const int*   ei  = (const int*)d_in[1];
    const float* w   = (const float*)d_in[2];
    float*       out = (float*)d_out;

    const size_t msg_bytes     = (size_t)N_EDGES * 2;                 // 12.8 MB
    const size_t partial_bytes = (size_t)RANGES * NB * RANGE_S * 2;   // 12.8 MB

    if (ws_size >= msg_bytes + partial_bytes) {
        unsigned short* msg     = (unsigned short*)d_ws;
        unsigned short* partial = (unsigned short*)((char*)d_ws + msg_bytes);
        transform_kernel<<<TBLOCKS, TTHREADS, 0, stream>>>(x, ei, w, msg);
        bin_kernel<<<RANGES * NB, BLK, 0, stream>>>(ei, msg, partial);
        reduce_range_kernel<<<(N_NODES / 4 + 255) / 256, 256, 0, stream>>>(partial, out);
    } else {
        zero_out_kernel<<<(N_NODES + 255) / 256, 256, 0, stream>>>(out, N_NODES);
        scatter_direct_kernel<<<(N_EDGES / 4 + 255) / 256, 256, 0, stream>>>(x, ei, w, out);
    }
}